// Round 7
// baseline (328.710 us; speedup 1.0000x reference)
//
#include <hip/hip_runtime.h>
#include <hip/hip_bf16.h>

// Problem constants
#define BB 4
#define CC 128
#define RN 4096
#define KK 16
#define NROWS (BB*RN*KK)   // 262144
#define EPSV 1e-5f

typedef __attribute__((ext_vector_type(8))) short short8;
typedef __attribute__((ext_vector_type(4))) float f32x4;

__device__ inline ushort f2bf(float f) {
    union { __hip_bfloat16 h; ushort u; } cv;
    cv.h = __float2bfloat16(f);
    return cv.u;
}

__device__ inline float readlane_f(float v, int src) {
    return __uint_as_float((uint)__builtin_amdgcn_readlane((int)__float_as_uint(v), src));
}

// ---------------- workspace layout (float indices) ----------------
// [0, 16384)          bn2 slots: 64 slots x 128 ch x {sum, sumsq}
// [16384, 17152)      stat slots: 64 slots x 12
// [17152, 17568)      params: scale1[64] shift1[64] scalew[16] shiftw[16] scale2[128] shift2[128]
// [17664, 29952)      W2 bf16 (128x192 ushort)
// [32768, 98304)      qpack: 16384 x float4
// [98304, 360448)     idx: 262144 int
// [360448, 622592)    zw_raw: 262144 f32
// [622592, 1671168)   ft bf16: (B,N,128) ushort

// merged: blocks [0,64) do qpack prep; blocks [64,160) do W2 bf16 cast
__global__ void k_prep(const float* __restrict__ Q, float4* __restrict__ qp,
                       const float* __restrict__ W2, ushort* __restrict__ W2b) {
    int blk = blockIdx.x;
    if (blk < 64) {
        int gid = blk * 256 + threadIdx.x;
        int b = gid >> 12, n = gid & (RN - 1);
        size_t base = (size_t)b * 3 * RN;
        float x = Q[base + n], y = Q[base + RN + n], z = Q[base + 2 * RN + n];
        qp[gid] = make_float4(x, y, z, fmaf(x, x, fmaf(y, y, z * z)));
    } else {
        int i = (blk - 64) * 256 + threadIdx.x;
        if (i < 128 * 192) W2b[i] = f2bf(W2[i]);
    }
}

__global__ void k_transpose(const float* __restrict__ FE, ushort* __restrict__ ftb) {
    __shared__ float t[32][33];
    int bid = blockIdx.x;
    int b = bid >> 9;
    int cb = (bid >> 7) & 3;
    int nb = bid & 127;
    int c0 = cb * 32, n0 = nb * 32;
    int tid = threadIdx.x;
    for (int o = tid; o < 1024; o += 256) {
        int i = o >> 5, j = o & 31;
        t[i][j] = FE[((size_t)b * CC + c0 + i) * RN + n0 + j];
    }
    __syncthreads();
    for (int o = tid; o < 512; o += 256) {
        int j = o >> 4, i2 = (o & 15) * 2;
        uint p = (uint)f2bf(t[i2][j]) | ((uint)f2bf(t[i2 + 1][j]) << 16);
        *(uint*)(ftb + ((size_t)(b * RN + n0 + j) * 128 + c0 + i2)) = p;
    }
}

// r4 winner: one wave per query row (4 rows/block). Bitonic-sorted init;
// ballot scan; readlane broadcast; early-issued ds_bpermute shifts.
__global__ __launch_bounds__(256) void k_knn(const float4* __restrict__ qp, int* __restrict__ idxout,
                                             float* __restrict__ zwout, float* __restrict__ statslots,
                                             const float* __restrict__ Ww, const float* __restrict__ bw) {
    __shared__ float bacc[9];
    const int tid = threadIdx.x;
    if (tid < 9) bacc[tid] = 0.f;
    __syncthreads();
    const int lane = tid & 63;
    const int wid = tid >> 6;
    const int row = blockIdx.x * 4 + wid;
    const int b = row >> 12, n = row & (RN - 1);
    const float4* qb = qp + b * RN;
    const float4 self = qb[n];
    const int upaddr = ((lane - 1) & 63) << 2;   // ds_bpermute byte addr for shift-up-by-1

    float ld; int li;
    {   // ---- bitonic sort of candidates 0..63 by (d2, idx) ascending ----
        float4 cp = qb[lane];
        ld = self.w + cp.w - 2.f * fmaf(self.x, cp.x, fmaf(self.y, cp.y, self.z * cp.z));
        li = lane;
        #pragma unroll
        for (int k = 2; k <= 64; k <<= 1) {
            #pragma unroll
            for (int j = k >> 1; j > 0; j >>= 1) {
                float od = __shfl_xor(ld, j);
                int   oi = __shfl_xor(li, j);
                bool up    = ((lane & k) == 0);
                bool lower = ((lane & j) == 0);
                bool myless = (ld < od) || (ld == od && li < oi);
                bool keep = (myless == lower) == up;
                if (!keep) { ld = od; li = oi; }
            }
        }
    }
    float g15d = readlane_f(ld, 15);
    int   g15i = __builtin_amdgcn_readlane(li, 15);

    float4 cur = qb[64 + lane];
    for (int t0 = 64; t0 < RN; t0 += 64) {
        float4 nxt = qb[t0 + 64 + lane];   // prefetch; last-iter overrun stays inside ws
        const float d2 = self.w + cur.w - 2.f * fmaf(self.x, cur.x, fmaf(self.y, cur.y, self.z * cur.z));
        bool beats = (d2 < g15d) || (d2 == g15d && (t0 + lane) < g15i);
        unsigned long long mask = __ballot(beats);
        if (mask) {
            do {
                float sd = __uint_as_float((uint)__builtin_amdgcn_ds_bpermute(upaddr, (int)__float_as_uint(ld)));
                int   si = __builtin_amdgcn_ds_bpermute(upaddr, li);
                int src = (int)__builtin_ctzll(mask);
                mask &= mask - 1;
                float cd = readlane_f(d2, src);   // SGPR broadcast
                int   ci = t0 + src;              // pure scalar
                bool lt2 = (ld < cd) || (ld == cd && li < ci);
                int p = (int)__builtin_popcountll(__ballot(lt2) & 0xFFFFull);
                if (lane == p)      { ld = cd; li = ci; }
                else if (lane > p)  { ld = sd; li = si; }
            } while (mask);
            g15d = readlane_f(ld, 15);
            g15i = __builtin_amdgcn_readlane(li, 15);
        }
        cur = nxt;
    }

    float sx = 0.f, sy = 0.f, sz = 0.f;
    if (lane < 16) {
        idxout[row * 16 + lane] = li;
        float4 pn = qb[li];
        sx = pn.x - self.x; sy = pn.y - self.y; sz = pn.z - self.z;
        float zw = fmaf(Ww[lane * 3], sx, fmaf(Ww[lane * 3 + 1], sy, fmaf(Ww[lane * 3 + 2], sz, bw[lane])));
        zwout[row * 16 + lane] = zw;
    }
    float vals[9] = {sx, sy, sz, sx * sx, sx * sy, sx * sz, sy * sy, sy * sz, sz * sz};
    #pragma unroll
    for (int i = 0; i < 9; ++i) {
        float v = vals[i];
        for (int off = 32; off; off >>= 1) v += __shfl_down(v, off);
        if (lane == 0) atomicAdd(&bacc[i], v);
    }
    __syncthreads();
    if (tid < 9) atomicAdd(&statslots[(blockIdx.x & 63) * 12 + tid], bacc[tid]);
}

// Analytic BN1 / BNw stats from the 12 moments.
__global__ void k_bn1(const float* __restrict__ slots, const float* __restrict__ W1, const float* __restrict__ b1,
                      const float* __restrict__ g1, const float* __restrict__ be1,
                      const float* __restrict__ Ww, const float* __restrict__ bw,
                      const float* __restrict__ gw, const float* __restrict__ bew, float* __restrict__ par) {
    __shared__ float st[12];
    int tid = threadIdx.x;
    if (tid < 12) {
        float s = 0.f;
        for (int i = 0; i < 64; ++i) s += slots[i * 12 + tid];
        st[tid] = s;
    }
    __syncthreads();
    const float invN = 1.0f / (float)NROWS;
    float mx = st[0] * invN, my = st[1] * invN, mz = st[2] * invN;
    float Cxx = st[3] * invN - mx * mx, Cxy = st[4] * invN - mx * my, Cxz = st[5] * invN - mx * mz;
    float Cyy = st[6] * invN - my * my, Cyz = st[7] * invN - my * mz, Czz = st[8] * invN - mz * mz;
    if (tid < 64) {
        float w0 = W1[tid * 3], w1 = W1[tid * 3 + 1], w2 = W1[tid * 3 + 2];
        float mean = w0 * mx + w1 * my + w2 * mz + b1[tid];
        float var = w0 * w0 * Cxx + w1 * w1 * Cyy + w2 * w2 * Czz
                  + 2.f * (w0 * w1 * Cxy + w0 * w2 * Cxz + w1 * w2 * Cyz);
        float sc = g1[tid] * rsqrtf(var + EPSV);
        par[tid] = sc;
        par[64 + tid] = be1[tid] - mean * sc;
    } else if (tid < 80) {
        int k = tid - 64;
        float w0 = Ww[k * 3], w1 = Ww[k * 3 + 1], w2 = Ww[k * 3 + 2];
        float mean = w0 * mx + w1 * my + w2 * mz + bw[k];
        float var = w0 * w0 * Cxx + w1 * w1 * Cyy + w2 * w2 * Czz
                  + 2.f * (w0 * w1 * Cxy + w0 * w2 * Cxz + w1 * w2 * Cyz);
        float sc = gw[k] * rsqrtf(var + EPSV);
        par[128 + k] = sc;
        par[144 + k] = bew[k] - mean * sc;
    }
}

// Pass A: gather + MFMA, BN2 partial stats ONLY (z2 never materialized).
__global__ __launch_bounds__(256, 4) void k_stats(const ushort* __restrict__ ftb, const int* __restrict__ idxb,
                                                  const float4* __restrict__ qp, const float* __restrict__ W1,
                                                  const float* __restrict__ b1, const ushort* __restrict__ W2b,
                                                  const float* __restrict__ b2, const float* __restrict__ par,
                                                  float* __restrict__ bn2slots) {
    __shared__ ushort enc_lds[64][72];   // 144B row stride
    __shared__ float subs[64][3];
    __shared__ int nbr[64];
    const int tid = threadIdx.x;
    const int bid = blockIdx.x;
    const int pair0 = bid * 4;
    const int b = pair0 >> 12;

    if (tid < 64) {
        int g = tid >> 4, k = tid & 15;
        int pair = pair0 + g;
        int n = idxb[pair * 16 + k];
        nbr[tid] = n;
        float4 pn = qp[b * RN + n];
        float4 ps = qp[pair];
        subs[tid][0] = pn.x - ps.x;
        subs[tid][1] = pn.y - ps.y;
        subs[tid][2] = pn.z - ps.z;
    }
    __syncthreads();
    for (int o = tid; o < 2048; o += 256) {
        int r = o >> 5, c2 = (o & 31) * 2;
        float z0 = fmaf(W1[c2 * 3],     subs[r][0], fmaf(W1[c2 * 3 + 1], subs[r][1], fmaf(W1[c2 * 3 + 2], subs[r][2], b1[c2])));
        float z1 = fmaf(W1[c2 * 3 + 3], subs[r][0], fmaf(W1[c2 * 3 + 4], subs[r][1], fmaf(W1[c2 * 3 + 5], subs[r][2], b1[c2 + 1])));
        float e0 = fmaxf(fmaf(z0, par[c2],     par[64 + c2]),     0.f);
        float e1 = fmaxf(fmaf(z1, par[c2 + 1], par[64 + c2 + 1]), 0.f);
        *(uint*)&enc_lds[r][c2] = (uint)f2bf(e0) | ((uint)f2bf(e1) << 16);
    }
    __syncthreads();

    const int lane = tid & 63, w = tid >> 6;
    const int lr = lane & 15, lg = lane >> 4;
    const int cbase = w * 32;

    short8 af[12];
    #pragma unroll
    for (int ct = 0; ct < 2; ++ct)
        #pragma unroll
        for (int kt = 0; kt < 6; ++kt)
            af[ct * 6 + kt] = *(const short8*)(W2b + (size_t)(cbase + ct * 16 + lr) * 192 + kt * 32 + lg * 8);

    float4 b2v[2];
    b2v[0] = *(const float4*)&b2[cbase + lg * 4];
    b2v[1] = *(const float4*)&b2[cbase + 16 + lg * 4];

    float st_s[8], st_q[8];
    #pragma unroll
    for (int i = 0; i < 8; ++i) { st_s[i] = 0.f; st_q[i] = 0.f; }

    #pragma unroll
    for (int nt = 0; nt < 4; ++nt) {
        const int r = nt * 16 + lr;
        const ushort* fr = ftb + ((size_t)(b * RN + nbr[r]) * 128) + lg * 8;
        short8 bf[6];
        bf[0] = *(const short8*)(fr);
        bf[1] = *(const short8*)(fr + 32);
        bf[2] = *(const short8*)(fr + 64);
        bf[3] = *(const short8*)(fr + 96);
        bf[4] = *(const short8*)&enc_lds[r][lg * 8];
        bf[5] = *(const short8*)&enc_lds[r][32 + lg * 8];
        #pragma unroll
        for (int ct = 0; ct < 2; ++ct) {
            f32x4 acc = {0.f, 0.f, 0.f, 0.f};
            #pragma unroll
            for (int kt = 0; kt < 6; ++kt)
                acc = __builtin_amdgcn_mfma_f32_16x16x32_bf16(af[ct * 6 + kt], bf[kt], acc, 0, 0, 0);
            const float4 bb = b2v[ct];
            float vb[4] = {bb.x, bb.y, bb.z, bb.w};
            #pragma unroll
            for (int cc = 0; cc < 4; ++cc) {
                float v = acc[cc] + vb[cc];
                st_s[ct * 4 + cc] += v;
                st_q[ct * 4 + cc] = fmaf(v, v, st_q[ct * 4 + cc]);
            }
        }
    }
    #pragma unroll
    for (int i = 0; i < 8; ++i) {
        float s = st_s[i], q = st_q[i];
        #pragma unroll
        for (int m = 1; m < 16; m <<= 1) { s += __shfl_xor(s, m); q += __shfl_xor(q, m); }
        if (lr == 0) {
            int ct = i >> 2, cc = i & 3;
            int c = cbase + ct * 16 + lg * 4 + cc;
            atomicAdd(&bn2slots[(bid & 63) * 256 + c * 2], s);
            atomicAdd(&bn2slots[(bid & 63) * 256 + c * 2 + 1], q);
        }
    }
}

__global__ void k_bn2(const float* __restrict__ slots, const float* __restrict__ g2,
                      const float* __restrict__ be2, float* __restrict__ par) {
    __shared__ float red[256];
    int tid = threadIdx.x;
    float v = 0.f;
    for (int s = 0; s < 64; ++s) v += slots[s * 256 + tid];
    red[tid] = v;
    __syncthreads();
    if (tid < 128) {
        const float invN = 1.0f / (float)NROWS;
        float mean = red[2 * tid] * invN;
        float var = red[2 * tid + 1] * invN - mean * mean;
        float sc = g2[tid] * rsqrtf(var + EPSV);
        par[160 + tid] = sc;
        par[288 + tid] = be2[tid] - mean * sc;
    }
}

// Pass B: recompute z2 in registers, fuse BN2+ReLU + w_diag + K-reduce +
// residual + transpose. out writes are coalesced float4 via a tiny LDS tile.
__global__ __launch_bounds__(256, 4) void k_fuse(const ushort* __restrict__ ftb, const int* __restrict__ idxb,
                                                 const float4* __restrict__ qp, const float* __restrict__ W1,
                                                 const float* __restrict__ b1, const ushort* __restrict__ W2b,
                                                 const float* __restrict__ b2, const float* __restrict__ par,
                                                 const float* __restrict__ zw_raw, const float* __restrict__ F_E,
                                                 float* __restrict__ out) {
    __shared__ ushort enc_lds[64][72];
    __shared__ float subs[64][3];
    __shared__ int nbr[64];
    __shared__ float outs[128][4];
    const int tid = threadIdx.x;
    const int bid = blockIdx.x;
    const int pair0 = bid * 4;
    const int b = pair0 >> 12;
    const int n0 = pair0 & (RN - 1);

    if (tid < 64) {
        int g = tid >> 4, k = tid & 15;
        int pair = pair0 + g;
        int n = idxb[pair * 16 + k];
        nbr[tid] = n;
        float4 pn = qp[b * RN + n];
        float4 ps = qp[pair];
        subs[tid][0] = pn.x - ps.x;
        subs[tid][1] = pn.y - ps.y;
        subs[tid][2] = pn.z - ps.z;
    }
    __syncthreads();
    for (int o = tid; o < 2048; o += 256) {
        int r = o >> 5, c2 = (o & 31) * 2;
        float z0 = fmaf(W1[c2 * 3],     subs[r][0], fmaf(W1[c2 * 3 + 1], subs[r][1], fmaf(W1[c2 * 3 + 2], subs[r][2], b1[c2])));
        float z1 = fmaf(W1[c2 * 3 + 3], subs[r][0], fmaf(W1[c2 * 3 + 4], subs[r][1], fmaf(W1[c2 * 3 + 5], subs[r][2], b1[c2 + 1])));
        float e0 = fmaxf(fmaf(z0, par[c2],     par[64 + c2]),     0.f);
        float e1 = fmaxf(fmaf(z1, par[c2 + 1], par[64 + c2 + 1]), 0.f);
        *(uint*)&enc_lds[r][c2] = (uint)f2bf(e0) | ((uint)f2bf(e1) << 16);
    }
    __syncthreads();

    const int lane = tid & 63, w = tid >> 6;
    const int lr = lane & 15, lg = lane >> 4;
    const int cbase = w * 32;

    short8 af[12];
    #pragma unroll
    for (int ct = 0; ct < 2; ++ct)
        #pragma unroll
        for (int kt = 0; kt < 6; ++kt)
            af[ct * 6 + kt] = *(const short8*)(W2b + (size_t)(cbase + ct * 16 + lr) * 192 + kt * 32 + lg * 8);

    float4 b2v[2], s2v[2], h2v[2];
    b2v[0] = *(const float4*)&b2[cbase + lg * 4];
    b2v[1] = *(const float4*)&b2[cbase + 16 + lg * 4];
    s2v[0] = *(const float4*)&par[160 + cbase + lg * 4];
    s2v[1] = *(const float4*)&par[160 + cbase + 16 + lg * 4];
    h2v[0] = *(const float4*)&par[288 + cbase + lg * 4];
    h2v[1] = *(const float4*)&par[288 + cbase + 16 + lg * 4];
    const float scw = par[128 + lr], shw = par[144 + lr];

    #pragma unroll
    for (int nt = 0; nt < 4; ++nt) {
        const int r = nt * 16 + lr;
        const ushort* fr = ftb + ((size_t)(b * RN + nbr[r]) * 128) + lg * 8;
        short8 bf[6];
        bf[0] = *(const short8*)(fr);
        bf[1] = *(const short8*)(fr + 32);
        bf[2] = *(const short8*)(fr + 64);
        bf[3] = *(const short8*)(fr + 96);
        bf[4] = *(const short8*)&enc_lds[r][lg * 8];
        bf[5] = *(const short8*)&enc_lds[r][32 + lg * 8];
        const float wdv = fmaxf(fmaf(zw_raw[(size_t)(pair0 + nt) * 16 + lr], scw, shw), 0.f);
        #pragma unroll
        for (int ct = 0; ct < 2; ++ct) {
            f32x4 acc = {0.f, 0.f, 0.f, 0.f};
            #pragma unroll
            for (int kt = 0; kt < 6; ++kt)
                acc = __builtin_amdgcn_mfma_f32_16x16x32_bf16(af[ct * 6 + kt], bf[kt], acc, 0, 0, 0);
            const float4 bb = b2v[ct];
            const float4 ss = s2v[ct];
            const float4 hh = h2v[ct];
            float vb[4] = {bb.x, bb.y, bb.z, bb.w};
            float vs[4] = {ss.x, ss.y, ss.z, ss.w};
            float vh[4] = {hh.x, hh.y, hh.z, hh.w};
            float y[4];
            #pragma unroll
            for (int cc = 0; cc < 4; ++cc) {
                float v = acc[cc] + vb[cc];
                y[cc] = fmaxf(fmaf(v, vs[cc], vh[cc]), 0.f) * wdv;
            }
            #pragma unroll
            for (int m = 1; m < 16; m <<= 1) {
                #pragma unroll
                for (int cc = 0; cc < 4; ++cc) y[cc] += __shfl_xor(y[cc], m);
            }
            if (lr == 0) {
                const int c0 = cbase + ct * 16 + lg * 4;
                #pragma unroll
                for (int cc = 0; cc < 4; ++cc) outs[c0 + cc][nt] = y[cc];
            }
        }
    }
    __syncthreads();
    if (tid < 128) {
        size_t base = ((size_t)b * CC + tid) * RN + n0;
        float4 o4 = *(float4*)&outs[tid][0];
        float4 fe4 = *(const float4*)&F_E[base];
        *(float4*)&out[base] = make_float4(o4.x + fe4.x, o4.y + fe4.y, o4.z + fe4.z, o4.w + fe4.w);
    }
}

extern "C" void kernel_launch(void* const* d_in, const int* in_sizes, int n_in,
                              void* d_out, int out_size, void* d_ws, size_t ws_size,
                              hipStream_t stream) {
    const float* F_E = (const float*)d_in[0];
    const float* Qp  = (const float*)d_in[1];
    const float* W1  = (const float*)d_in[2];
    const float* b1  = (const float*)d_in[3];
    const float* g1  = (const float*)d_in[4];
    const float* be1 = (const float*)d_in[5];
    const float* W2  = (const float*)d_in[6];
    const float* b2  = (const float*)d_in[7];
    const float* g2  = (const float*)d_in[8];
    const float* be2 = (const float*)d_in[9];
    const float* Ww  = (const float*)d_in[10];
    const float* bw  = (const float*)d_in[11];
    const float* gw  = (const float*)d_in[12];
    const float* bew = (const float*)d_in[13];
    float* out = (float*)d_out;
    float* wsf = (float*)d_ws;

    float* bn2slots   = wsf;
    float* statslots  = wsf + 16384;
    float* par        = wsf + 17152;
    ushort* W2b       = (ushort*)(wsf + 17664);
    float4* qpack     = (float4*)(wsf + 32768);
    int* idxb         = (int*)(wsf + 98304);
    float* zw_raw     = wsf + 360448;
    ushort* ftb       = (ushort*)(wsf + 622592);

    hipMemsetAsync(d_ws, 0, 17152 * sizeof(float), stream);
    k_prep<<<160, 256, 0, stream>>>(Qp, qpack, W2, W2b);
    k_transpose<<<2048, 256, 0, stream>>>(F_E, ftb);
    k_knn<<<4096, 256, 0, stream>>>(qpack, idxb, zw_raw, statslots, Ww, bw);
    k_bn1<<<1, 128, 0, stream>>>(statslots, W1, b1, g1, be1, Ww, bw, gw, bew, par);
    k_stats<<<4096, 256, 0, stream>>>(ftb, idxb, qpack, W1, b1, W2b, b2, par, bn2slots);
    k_bn2<<<1, 256, 0, stream>>>(bn2slots, g2, be2, par);
    k_fuse<<<4096, 256, 0, stream>>>(ftb, idxb, qpack, W1, b1, W2b, b2, par, zw_raw, F_E, out);
}

// Round 8
// 273.084 us; speedup vs baseline: 1.2037x; 1.2037x over previous
//
#include <hip/hip_runtime.h>
#include <hip/hip_bf16.h>

// Problem constants
#define BB 4
#define CC 128
#define RN 4096
#define KK 16
#define NROWS (BB*RN*KK)   // 262144
#define EPSV 1e-5f

typedef __attribute__((ext_vector_type(8))) short short8;
typedef __attribute__((ext_vector_type(4))) float f32x4;

__device__ inline ushort f2bf(float f) {
    union { __hip_bfloat16 h; ushort u; } cv;
    cv.h = __float2bfloat16(f);
    return cv.u;
}

__device__ inline float readlane_f(float v, int src) {
    return __uint_as_float((uint)__builtin_amdgcn_readlane((int)__float_as_uint(v), src));
}

// ---------------- workspace layout (float indices) ----------------
// [0, 16384)          bn2 slots: 64 slots x 128 ch x {sum, sumsq}
// [16384, 17152)      stat slots: 64 slots x 12
// [17152, 17568)      params: scale1[64] shift1[64] scalew[16] shiftw[16] scale2[128] shift2[128]
// [17664, 29952)      W2 bf16 (128x192 ushort)
// [32768, 98304)      qpack: 16384 x float4
// [98304, 360448)     idx: 262144 int
// [360448, 622592)    zw_raw: 262144 f32
// [622592, 1671168)   ft bf16: (B,N,128) ushort
// [1671168, ...)      z2: 262144 x 128 bf16 (67.1 MB)

// merged: blocks [0,64) do qpack prep; blocks [64,160) do W2 bf16 cast
__global__ void k_prep(const float* __restrict__ Q, float4* __restrict__ qp,
                       const float* __restrict__ W2, ushort* __restrict__ W2b) {
    int blk = blockIdx.x;
    if (blk < 64) {
        int gid = blk * 256 + threadIdx.x;
        int b = gid >> 12, n = gid & (RN - 1);
        size_t base = (size_t)b * 3 * RN;
        float x = Q[base + n], y = Q[base + RN + n], z = Q[base + 2 * RN + n];
        qp[gid] = make_float4(x, y, z, fmaf(x, x, fmaf(y, y, z * z)));
    } else {
        int i = (blk - 64) * 256 + threadIdx.x;
        if (i < 128 * 192) W2b[i] = f2bf(W2[i]);
    }
}

__global__ void k_transpose(const float* __restrict__ FE, ushort* __restrict__ ftb) {
    __shared__ float t[32][33];
    int bid = blockIdx.x;
    int b = bid >> 9;
    int cb = (bid >> 7) & 3;
    int nb = bid & 127;
    int c0 = cb * 32, n0 = nb * 32;
    int tid = threadIdx.x;
    for (int o = tid; o < 1024; o += 256) {
        int i = o >> 5, j = o & 31;
        t[i][j] = FE[((size_t)b * CC + c0 + i) * RN + n0 + j];
    }
    __syncthreads();
    for (int o = tid; o < 512; o += 256) {
        int j = o >> 4, i2 = (o & 15) * 2;
        uint p = (uint)f2bf(t[i2][j]) | ((uint)f2bf(t[i2 + 1][j]) << 16);
        *(uint*)(ftb + ((size_t)(b * RN + n0 + j) * 128 + c0 + i2)) = p;
    }
}

// r4 winner: one wave per query row (4 rows/block). Bitonic-sorted init;
// ballot scan; readlane broadcast; early-issued ds_bpermute shifts.
__global__ __launch_bounds__(256) void k_knn(const float4* __restrict__ qp, int* __restrict__ idxout,
                                             float* __restrict__ zwout, float* __restrict__ statslots,
                                             const float* __restrict__ Ww, const float* __restrict__ bw) {
    __shared__ float bacc[9];
    const int tid = threadIdx.x;
    if (tid < 9) bacc[tid] = 0.f;
    __syncthreads();
    const int lane = tid & 63;
    const int wid = tid >> 6;
    const int row = blockIdx.x * 4 + wid;
    const int b = row >> 12, n = row & (RN - 1);
    const float4* qb = qp + b * RN;
    const float4 self = qb[n];
    const int upaddr = ((lane - 1) & 63) << 2;   // ds_bpermute byte addr for shift-up-by-1

    float ld; int li;
    {   // ---- bitonic sort of candidates 0..63 by (d2, idx) ascending ----
        float4 cp = qb[lane];
        ld = self.w + cp.w - 2.f * fmaf(self.x, cp.x, fmaf(self.y, cp.y, self.z * cp.z));
        li = lane;
        #pragma unroll
        for (int k = 2; k <= 64; k <<= 1) {
            #pragma unroll
            for (int j = k >> 1; j > 0; j >>= 1) {
                float od = __shfl_xor(ld, j);
                int   oi = __shfl_xor(li, j);
                bool up    = ((lane & k) == 0);
                bool lower = ((lane & j) == 0);
                bool myless = (ld < od) || (ld == od && li < oi);
                bool keep = (myless == lower) == up;
                if (!keep) { ld = od; li = oi; }
            }
        }
    }
    float g15d = readlane_f(ld, 15);
    int   g15i = __builtin_amdgcn_readlane(li, 15);

    float4 cur = qb[64 + lane];
    for (int t0 = 64; t0 < RN; t0 += 64) {
        float4 nxt = qb[t0 + 64 + lane];   // prefetch; last-iter overrun stays inside ws
        const float d2 = self.w + cur.w - 2.f * fmaf(self.x, cur.x, fmaf(self.y, cur.y, self.z * cur.z));
        bool beats = (d2 < g15d) || (d2 == g15d && (t0 + lane) < g15i);
        unsigned long long mask = __ballot(beats);
        if (mask) {
            do {
                float sd = __uint_as_float((uint)__builtin_amdgcn_ds_bpermute(upaddr, (int)__float_as_uint(ld)));
                int   si = __builtin_amdgcn_ds_bpermute(upaddr, li);
                int src = (int)__builtin_ctzll(mask);
                mask &= mask - 1;
                float cd = readlane_f(d2, src);   // SGPR broadcast
                int   ci = t0 + src;              // pure scalar
                bool lt2 = (ld < cd) || (ld == cd && li < ci);
                int p = (int)__builtin_popcountll(__ballot(lt2) & 0xFFFFull);
                if (lane == p)      { ld = cd; li = ci; }
                else if (lane > p)  { ld = sd; li = si; }
            } while (mask);
            g15d = readlane_f(ld, 15);
            g15i = __builtin_amdgcn_readlane(li, 15);
        }
        cur = nxt;
    }

    float sx = 0.f, sy = 0.f, sz = 0.f;
    if (lane < 16) {
        idxout[row * 16 + lane] = li;
        float4 pn = qb[li];
        sx = pn.x - self.x; sy = pn.y - self.y; sz = pn.z - self.z;
        float zw = fmaf(Ww[lane * 3], sx, fmaf(Ww[lane * 3 + 1], sy, fmaf(Ww[lane * 3 + 2], sz, bw[lane])));
        zwout[row * 16 + lane] = zw;
    }
    float vals[9] = {sx, sy, sz, sx * sx, sx * sy, sx * sz, sy * sy, sy * sz, sz * sz};
    #pragma unroll
    for (int i = 0; i < 9; ++i) {
        float v = vals[i];
        for (int off = 32; off; off >>= 1) v += __shfl_down(v, off);
        if (lane == 0) atomicAdd(&bacc[i], v);
    }
    __syncthreads();
    if (tid < 9) atomicAdd(&statslots[(blockIdx.x & 63) * 12 + tid], bacc[tid]);
}

// Analytic BN1 / BNw stats from the 12 moments.
__global__ void k_bn1(const float* __restrict__ slots, const float* __restrict__ W1, const float* __restrict__ b1,
                      const float* __restrict__ g1, const float* __restrict__ be1,
                      const float* __restrict__ Ww, const float* __restrict__ bw,
                      const float* __restrict__ gw, const float* __restrict__ bew, float* __restrict__ par) {
    __shared__ float st[12];
    int tid = threadIdx.x;
    if (tid < 12) {
        float s = 0.f;
        for (int i = 0; i < 64; ++i) s += slots[i * 12 + tid];
        st[tid] = s;
    }
    __syncthreads();
    const float invN = 1.0f / (float)NROWS;
    float mx = st[0] * invN, my = st[1] * invN, mz = st[2] * invN;
    float Cxx = st[3] * invN - mx * mx, Cxy = st[4] * invN - mx * my, Cxz = st[5] * invN - mx * mz;
    float Cyy = st[6] * invN - my * my, Cyz = st[7] * invN - my * mz, Czz = st[8] * invN - mz * mz;
    if (tid < 64) {
        float w0 = W1[tid * 3], w1 = W1[tid * 3 + 1], w2 = W1[tid * 3 + 2];
        float mean = w0 * mx + w1 * my + w2 * mz + b1[tid];
        float var = w0 * w0 * Cxx + w1 * w1 * Cyy + w2 * w2 * Czz
                  + 2.f * (w0 * w1 * Cxy + w0 * w2 * Cxz + w1 * w2 * Cyz);
        float sc = g1[tid] * rsqrtf(var + EPSV);
        par[tid] = sc;
        par[64 + tid] = be1[tid] - mean * sc;
    } else if (tid < 80) {
        int k = tid - 64;
        float w0 = Ww[k * 3], w1 = Ww[k * 3 + 1], w2 = Ww[k * 3 + 2];
        float mean = w0 * mx + w1 * my + w2 * mz + bw[k];
        float var = w0 * w0 * Cxx + w1 * w1 * Cyy + w2 * w2 * Czz
                  + 2.f * (w0 * w1 * Cxy + w0 * w2 * Cxz + w1 * w2 * Cyz);
        float sc = gw[k] * rsqrtf(var + EPSV);
        par[128 + k] = sc;
        par[144 + k] = bew[k] - mean * sc;
    }
}

// Fused MFMA GEMM v3: XCD-swizzled tiles; all gather fragments issued up-front
// (latency overlapped by enc_sub VALU phase); z2 staged in LDS and stored as
// fully-coalesced 1KB-per-wave bursts; BN2 partial stats inline.
__global__ __launch_bounds__(256) void k_main(const ushort* __restrict__ ftb, const int* __restrict__ idxb,
                                              const float4* __restrict__ qp, const float* __restrict__ W1,
                                              const float* __restrict__ b1, const ushort* __restrict__ W2b,
                                              const float* __restrict__ b2, const float* __restrict__ par,
                                              float* __restrict__ bn2slots, __hip_bfloat16* __restrict__ z2) {
    __shared__ union {
        ushort enc[64][72];    // 144B row stride (2-way bank, free)
        ushort z2s[64][132];   // 264B row stride for staged stores
    } u;
    __shared__ float subs[64][3];
    __shared__ int nbr[64];
    const int tid = threadIdx.x;
    // bijective XCD swizzle: 4096 tiles, 8 XCDs, 512 contiguous tiles each
    const int tile = ((blockIdx.x & 7) << 9) | (blockIdx.x >> 3);
    const int pair0 = tile * 4;
    const int b = pair0 >> 12;
    const int lane = tid & 63, w = tid >> 6;
    const int lr = lane & 15, lg = lane >> 4;

    // prologue spread across all 4 waves: each wave loads its own query row
    if (lane < 16) {
        int pair = pair0 + w;
        int n = idxb[pair * 16 + lane];
        int r = w * 16 + lane;
        nbr[r] = n;
        float4 pn = qp[b * RN + n];
        float4 ps = qp[pair];
        subs[r][0] = pn.x - ps.x;
        subs[r][1] = pn.y - ps.y;
        subs[r][2] = pn.z - ps.z;
    }
    __syncthreads();

    // issue ALL 16 gather loads up-front; latency overlaps enc compute below
    short8 bfg[4][4];
    #pragma unroll
    for (int nt = 0; nt < 4; ++nt) {
        const ushort* fr = ftb + ((size_t)(b * RN + nbr[nt * 16 + lr]) * 128) + lg * 8;
        bfg[nt][0] = *(const short8*)(fr);
        bfg[nt][1] = *(const short8*)(fr + 32);
        bfg[nt][2] = *(const short8*)(fr + 64);
        bfg[nt][3] = *(const short8*)(fr + 96);
    }

    const int cbase = w * 32;
    short8 af[12];
    #pragma unroll
    for (int ct = 0; ct < 2; ++ct)
        #pragma unroll
        for (int kt = 0; kt < 6; ++kt)
            af[ct * 6 + kt] = *(const short8*)(W2b + (size_t)(cbase + ct * 16 + lr) * 192 + kt * 32 + lg * 8);

    // enc_sub -> u.enc (VALU work overlapping the in-flight gathers)
    for (int o = tid; o < 2048; o += 256) {
        int r = o >> 5, c2 = (o & 31) * 2;
        float z0 = fmaf(W1[c2 * 3],     subs[r][0], fmaf(W1[c2 * 3 + 1], subs[r][1], fmaf(W1[c2 * 3 + 2], subs[r][2], b1[c2])));
        float z1 = fmaf(W1[c2 * 3 + 3], subs[r][0], fmaf(W1[c2 * 3 + 4], subs[r][1], fmaf(W1[c2 * 3 + 5], subs[r][2], b1[c2 + 1])));
        float e0 = fmaxf(fmaf(z0, par[c2],     par[64 + c2]),     0.f);
        float e1 = fmaxf(fmaf(z1, par[c2 + 1], par[64 + c2 + 1]), 0.f);
        *(uint*)&u.enc[r][c2] = (uint)f2bf(e0) | ((uint)f2bf(e1) << 16);
    }
    __syncthreads();

    float4 b2v[2];
    b2v[0] = *(const float4*)&b2[cbase + lg * 4];
    b2v[1] = *(const float4*)&b2[cbase + 16 + lg * 4];

    float st_s[8], st_q[8];
    #pragma unroll
    for (int i = 0; i < 8; ++i) { st_s[i] = 0.f; st_q[i] = 0.f; }

    float accs[4][2][4];
    #pragma unroll
    for (int nt = 0; nt < 4; ++nt) {
        const int r = nt * 16 + lr;
        short8 be0 = *(const short8*)&u.enc[r][lg * 8];
        short8 be1 = *(const short8*)&u.enc[r][32 + lg * 8];
        #pragma unroll
        for (int ct = 0; ct < 2; ++ct) {
            f32x4 acc = {0.f, 0.f, 0.f, 0.f};
            acc = __builtin_amdgcn_mfma_f32_16x16x32_bf16(af[ct * 6 + 0], bfg[nt][0], acc, 0, 0, 0);
            acc = __builtin_amdgcn_mfma_f32_16x16x32_bf16(af[ct * 6 + 1], bfg[nt][1], acc, 0, 0, 0);
            acc = __builtin_amdgcn_mfma_f32_16x16x32_bf16(af[ct * 6 + 2], bfg[nt][2], acc, 0, 0, 0);
            acc = __builtin_amdgcn_mfma_f32_16x16x32_bf16(af[ct * 6 + 3], bfg[nt][3], acc, 0, 0, 0);
            acc = __builtin_amdgcn_mfma_f32_16x16x32_bf16(af[ct * 6 + 4], be0, acc, 0, 0, 0);
            acc = __builtin_amdgcn_mfma_f32_16x16x32_bf16(af[ct * 6 + 5], be1, acc, 0, 0, 0);
            const float4 bb = b2v[ct];
            float vb[4] = {bb.x, bb.y, bb.z, bb.w};
            #pragma unroll
            for (int cc = 0; cc < 4; ++cc) {
                float v = acc[cc] + vb[cc];
                accs[nt][ct][cc] = v;
                st_s[ct * 4 + cc] += v;
                st_q[ct * 4 + cc] = fmaf(v, v, st_q[ct * 4 + cc]);
            }
        }
    }
    __syncthreads();   // enc reads done everywhere; safe to overwrite with z2s

    // stage z2 tile into LDS (padded rows), then coalesced global stores
    #pragma unroll
    for (int nt = 0; nt < 4; ++nt) {
        #pragma unroll
        for (int ct = 0; ct < 2; ++ct) {
            union { __hip_bfloat16 h[4]; uint2 u2; } pk;
            #pragma unroll
            for (int cc = 0; cc < 4; ++cc) pk.h[cc] = __float2bfloat16(accs[nt][ct][cc]);
            *(uint2*)&u.z2s[nt * 16 + lr][cbase + ct * 16 + lg * 4] = pk.u2;
        }
    }
    __syncthreads();
    {
        __hip_bfloat16* zbase = z2 + (size_t)pair0 * 16 * CC;
        #pragma unroll
        for (int p = 0; p < 4; ++p) {
            int e = p * 256 + tid;                 // 16B unit index
            int row = e >> 4, unit = e & 15;
            uint2 v0 = *(uint2*)&u.z2s[row][unit * 8];
            uint2 v1 = *(((uint2*)&u.z2s[row][unit * 8]) + 1);
            *(uint4*)(zbase + (size_t)row * CC + unit * 8) = make_uint4(v0.x, v0.y, v1.x, v1.y);
        }
    }
    // BN2 partial stats: reduce over the 16 rows, one atomic per channel
    #pragma unroll
    for (int i = 0; i < 8; ++i) {
        float s = st_s[i], q = st_q[i];
        #pragma unroll
        for (int m = 1; m < 16; m <<= 1) { s += __shfl_xor(s, m); q += __shfl_xor(q, m); }
        if (lr == 0) {
            int ct = i >> 2, cc = i & 3;
            int c = cbase + ct * 16 + lg * 4 + cc;
            atomicAdd(&bn2slots[(tile & 63) * 256 + c * 2], s);
            atomicAdd(&bn2slots[(tile & 63) * 256 + c * 2 + 1], q);
        }
    }
}

__global__ void k_bn2(const float* __restrict__ slots, const float* __restrict__ g2,
                      const float* __restrict__ be2, float* __restrict__ par) {
    __shared__ float red[256];
    int tid = threadIdx.x;
    float v = 0.f;
    for (int s = 0; s < 64; ++s) v += slots[s * 256 + tid];
    red[tid] = v;
    __syncthreads();
    if (tid < 128) {
        const float invN = 1.0f / (float)NROWS;
        float mean = red[2 * tid] * invN;
        float var = red[2 * tid + 1] * invN - mean * mean;
        float sc = g2[tid] * rsqrtf(var + EPSV);
        par[160 + tid] = sc;
        par[288 + tid] = be2[tid] - mean * sc;
    }
}

// Epilogue: BN2+ReLU, weight by w_diag, sum over K, residual, transpose to (B,C,N).
__global__ __launch_bounds__(256) void k_out(const __hip_bfloat16* __restrict__ z2, const float* __restrict__ zw_raw,
                                             const float* __restrict__ par, const float* __restrict__ F_E,
                                             float* __restrict__ out) {
    __shared__ float wd[32][16];
    __shared__ float outs[32][129];
    const int tid = threadIdx.x;
    const int b = blockIdx.x >> 7;
    const int r0 = (blockIdx.x & 127) * 32;
    const int rowbase = (b * RN + r0) * 16;
    for (int o = tid; o < 512; o += 256) {
        int rr = o >> 4, k = o & 15;
        wd[rr][k] = fmaxf(fmaf(zw_raw[rowbase + o], par[128 + k], par[144 + k]), 0.f);
    }
    __syncthreads();
    const int c0 = (tid & 63) * 2;
    const int rh = tid >> 6;
    const float sc0 = par[160 + c0], sh0 = par[288 + c0];
    const float sc1 = par[160 + c0 + 1], sh1 = par[288 + c0 + 1];
    for (int rr = rh; rr < 32; rr += 4) {
        float a0 = 0.f, a1 = 0.f;
        const __hip_bfloat16* zp = z2 + ((size_t)rowbase + rr * 16) * CC + c0;
        #pragma unroll
        for (int k = 0; k < 16; ++k) {
            unsigned int uu = *(const unsigned int*)(zp + k * CC);
            float z0 = __uint_as_float(uu << 16);
            float z1 = __uint_as_float(uu & 0xFFFF0000u);
            float w = wd[rr][k];
            a0 += fmaxf(fmaf(z0, sc0, sh0), 0.f) * w;
            a1 += fmaxf(fmaf(z1, sc1, sh1), 0.f) * w;
        }
        outs[rr][c0] = a0; outs[rr][c0 + 1] = a1;
    }
    __syncthreads();
    for (int o = tid; o < 4096; o += 256) {
        int c = o >> 5, rr = o & 31;
        size_t oi = ((size_t)b * CC + c) * RN + r0 + rr;
        out[oi] = outs[rr][c] + F_E[oi];
    }
}

extern "C" void kernel_launch(void* const* d_in, const int* in_sizes, int n_in,
                              void* d_out, int out_size, void* d_ws, size_t ws_size,
                              hipStream_t stream) {
    const float* F_E = (const float*)d_in[0];
    const float* Qp  = (const float*)d_in[1];
    const float* W1  = (const float*)d_in[2];
    const float* b1  = (const float*)d_in[3];
    const float* g1  = (const float*)d_in[4];
    const float* be1 = (const float*)d_in[5];
    const float* W2  = (const float*)d_in[6];
    const float* b2  = (const float*)d_in[7];
    const float* g2  = (const float*)d_in[8];
    const float* be2 = (const float*)d_in[9];
    const float* Ww  = (const float*)d_in[10];
    const float* bw  = (const float*)d_in[11];
    const float* gw  = (const float*)d_in[12];
    const float* bew = (const float*)d_in[13];
    float* out = (float*)d_out;
    float* wsf = (float*)d_ws;

    float* bn2slots   = wsf;
    float* statslots  = wsf + 16384;
    float* par        = wsf + 17152;
    ushort* W2b       = (ushort*)(wsf + 17664);
    float4* qpack     = (float4*)(wsf + 32768);
    int* idxb         = (int*)(wsf + 98304);
    float* zw_raw     = wsf + 360448;
    ushort* ftb       = (ushort*)(wsf + 622592);
    __hip_bfloat16* z2 = (__hip_bfloat16*)(wsf + 1671168);

    hipMemsetAsync(d_ws, 0, 17152 * sizeof(float), stream);
    k_prep<<<160, 256, 0, stream>>>(Qp, qpack, W2, W2b);
    k_transpose<<<2048, 256, 0, stream>>>(F_E, ftb);
    k_knn<<<4096, 256, 0, stream>>>(qpack, idxb, zw_raw, statslots, Ww, bw);
    k_bn1<<<1, 128, 0, stream>>>(statslots, W1, b1, g1, be1, Ww, bw, gw, bew, par);
    k_main<<<4096, 256, 0, stream>>>(ftb, idxb, qpack, W1, b1, W2b, b2, par, bn2slots, z2);
    k_bn2<<<1, 256, 0, stream>>>(bn2slots, g2, be2, par);
    k_out<<<512, 256, 0, stream>>>(z2, zw_raw, par, F_E, out);
}

// Round 9
// 268.306 us; speedup vs baseline: 1.2251x; 1.0178x over previous
//
#include <hip/hip_runtime.h>
#include <hip/hip_bf16.h>

// Problem constants
#define BB 4
#define CC 128
#define RN 4096
#define KK 16
#define NROWS (BB*RN*KK)   // 262144
#define EPSV 1e-5f

typedef __attribute__((ext_vector_type(8))) short short8;
typedef __attribute__((ext_vector_type(4))) float f32x4;

__device__ inline ushort f2bf(float f) {
    union { __hip_bfloat16 h; ushort u; } cv;
    cv.h = __float2bfloat16(f);
    return cv.u;
}

__device__ inline float readlane_f(float v, int src) {
    return __uint_as_float((uint)__builtin_amdgcn_readlane((int)__float_as_uint(v), src));
}

// ---------------- workspace layout (float indices) ----------------
// [0, 16384)          bn2 slots: 64 slots x 128 ch x {sum, sumsq}
// [16384, 17152)      stat slots: 64 slots x 12
// [17152, 17568)      params: scale1[64] shift1[64] scalew[16] shiftw[16] scale2[128] shift2[128]
// [17664, 29952)      W2 bf16 (128x192 ushort)
// [32768, 98304)      qpack: 16384 x float4
// [98304, 360448)     idx: 262144 int
// [360448, 622592)    zw_raw: 262144 f32
// [622592, 1671168)   ft bf16: (B,N,128) ushort
// [1671168, ...)      z2: 262144 x 128 bf16 (67.1 MB)

// merged: blocks [0,64) do qpack prep; blocks [64,160) do W2 bf16 cast
__global__ void k_prep(const float* __restrict__ Q, float4* __restrict__ qp,
                       const float* __restrict__ W2, ushort* __restrict__ W2b) {
    int blk = blockIdx.x;
    if (blk < 64) {
        int gid = blk * 256 + threadIdx.x;
        int b = gid >> 12, n = gid & (RN - 1);
        size_t base = (size_t)b * 3 * RN;
        float x = Q[base + n], y = Q[base + RN + n], z = Q[base + 2 * RN + n];
        qp[gid] = make_float4(x, y, z, fmaf(x, x, fmaf(y, y, z * z)));
    } else {
        int i = (blk - 64) * 256 + threadIdx.x;
        if (i < 128 * 192) W2b[i] = f2bf(W2[i]);
    }
}

__global__ void k_transpose(const float* __restrict__ FE, ushort* __restrict__ ftb) {
    __shared__ float t[32][33];
    int bid = blockIdx.x;
    int b = bid >> 9;
    int cb = (bid >> 7) & 3;
    int nb = bid & 127;
    int c0 = cb * 32, n0 = nb * 32;
    int tid = threadIdx.x;
    for (int o = tid; o < 1024; o += 256) {
        int i = o >> 5, j = o & 31;
        t[i][j] = FE[((size_t)b * CC + c0 + i) * RN + n0 + j];
    }
    __syncthreads();
    for (int o = tid; o < 512; o += 256) {
        int j = o >> 4, i2 = (o & 15) * 2;
        uint p = (uint)f2bf(t[i2][j]) | ((uint)f2bf(t[i2 + 1][j]) << 16);
        *(uint*)(ftb + ((size_t)(b * RN + n0 + j) * 128 + c0 + i2)) = p;
    }
}

// r4 winner: one wave per query row (4 rows/block). Bitonic-sorted init;
// ballot scan; readlane broadcast; early-issued ds_bpermute shifts.
__global__ __launch_bounds__(256) void k_knn(const float4* __restrict__ qp, int* __restrict__ idxout,
                                             float* __restrict__ zwout, float* __restrict__ statslots,
                                             const float* __restrict__ Ww, const float* __restrict__ bw) {
    __shared__ float bacc[9];
    const int tid = threadIdx.x;
    if (tid < 9) bacc[tid] = 0.f;
    __syncthreads();
    const int lane = tid & 63;
    const int wid = tid >> 6;
    const int row = blockIdx.x * 4 + wid;
    const int b = row >> 12, n = row & (RN - 1);
    const float4* qb = qp + b * RN;
    const float4 self = qb[n];
    const int upaddr = ((lane - 1) & 63) << 2;   // ds_bpermute byte addr for shift-up-by-1

    float ld; int li;
    {   // ---- bitonic sort of candidates 0..63 by (d2, idx) ascending ----
        float4 cp = qb[lane];
        ld = self.w + cp.w - 2.f * fmaf(self.x, cp.x, fmaf(self.y, cp.y, self.z * cp.z));
        li = lane;
        #pragma unroll
        for (int k = 2; k <= 64; k <<= 1) {
            #pragma unroll
            for (int j = k >> 1; j > 0; j >>= 1) {
                float od = __shfl_xor(ld, j);
                int   oi = __shfl_xor(li, j);
                bool up    = ((lane & k) == 0);
                bool lower = ((lane & j) == 0);
                bool myless = (ld < od) || (ld == od && li < oi);
                bool keep = (myless == lower) == up;
                if (!keep) { ld = od; li = oi; }
            }
        }
    }
    float g15d = readlane_f(ld, 15);
    int   g15i = __builtin_amdgcn_readlane(li, 15);

    float4 cur = qb[64 + lane];
    for (int t0 = 64; t0 < RN; t0 += 64) {
        float4 nxt = qb[t0 + 64 + lane];   // prefetch; last-iter overrun stays inside ws
        const float d2 = self.w + cur.w - 2.f * fmaf(self.x, cur.x, fmaf(self.y, cur.y, self.z * cur.z));
        bool beats = (d2 < g15d) || (d2 == g15d && (t0 + lane) < g15i);
        unsigned long long mask = __ballot(beats);
        if (mask) {
            do {
                float sd = __uint_as_float((uint)__builtin_amdgcn_ds_bpermute(upaddr, (int)__float_as_uint(ld)));
                int   si = __builtin_amdgcn_ds_bpermute(upaddr, li);
                int src = (int)__builtin_ctzll(mask);
                mask &= mask - 1;
                float cd = readlane_f(d2, src);   // SGPR broadcast
                int   ci = t0 + src;              // pure scalar
                bool lt2 = (ld < cd) || (ld == cd && li < ci);
                int p = (int)__builtin_popcountll(__ballot(lt2) & 0xFFFFull);
                if (lane == p)      { ld = cd; li = ci; }
                else if (lane > p)  { ld = sd; li = si; }
            } while (mask);
            g15d = readlane_f(ld, 15);
            g15i = __builtin_amdgcn_readlane(li, 15);
        }
        cur = nxt;
    }

    float sx = 0.f, sy = 0.f, sz = 0.f;
    if (lane < 16) {
        idxout[row * 16 + lane] = li;
        float4 pn = qb[li];
        sx = pn.x - self.x; sy = pn.y - self.y; sz = pn.z - self.z;
        float zw = fmaf(Ww[lane * 3], sx, fmaf(Ww[lane * 3 + 1], sy, fmaf(Ww[lane * 3 + 2], sz, bw[lane])));
        zwout[row * 16 + lane] = zw;
    }
    float vals[9] = {sx, sy, sz, sx * sx, sx * sy, sx * sz, sy * sy, sy * sz, sz * sz};
    #pragma unroll
    for (int i = 0; i < 9; ++i) {
        float v = vals[i];
        for (int off = 32; off; off >>= 1) v += __shfl_down(v, off);
        if (lane == 0) atomicAdd(&bacc[i], v);
    }
    __syncthreads();
    if (tid < 9) atomicAdd(&statslots[(blockIdx.x & 63) * 12 + tid], bacc[tid]);
}

// Analytic BN1 / BNw stats from the 12 moments.
__global__ void k_bn1(const float* __restrict__ slots, const float* __restrict__ W1, const float* __restrict__ b1,
                      const float* __restrict__ g1, const float* __restrict__ be1,
                      const float* __restrict__ Ww, const float* __restrict__ bw,
                      const float* __restrict__ gw, const float* __restrict__ bew, float* __restrict__ par) {
    __shared__ float st[12];
    int tid = threadIdx.x;
    if (tid < 12) {
        float s = 0.f;
        for (int i = 0; i < 64; ++i) s += slots[i * 12 + tid];
        st[tid] = s;
    }
    __syncthreads();
    const float invN = 1.0f / (float)NROWS;
    float mx = st[0] * invN, my = st[1] * invN, mz = st[2] * invN;
    float Cxx = st[3] * invN - mx * mx, Cxy = st[4] * invN - mx * my, Cxz = st[5] * invN - mx * mz;
    float Cyy = st[6] * invN - my * my, Cyz = st[7] * invN - my * mz, Czz = st[8] * invN - mz * mz;
    if (tid < 64) {
        float w0 = W1[tid * 3], w1 = W1[tid * 3 + 1], w2 = W1[tid * 3 + 2];
        float mean = w0 * mx + w1 * my + w2 * mz + b1[tid];
        float var = w0 * w0 * Cxx + w1 * w1 * Cyy + w2 * w2 * Czz
                  + 2.f * (w0 * w1 * Cxy + w0 * w2 * Cxz + w1 * w2 * Cyz);
        float sc = g1[tid] * rsqrtf(var + EPSV);
        par[tid] = sc;
        par[64 + tid] = be1[tid] - mean * sc;
    } else if (tid < 80) {
        int k = tid - 64;
        float w0 = Ww[k * 3], w1 = Ww[k * 3 + 1], w2 = Ww[k * 3 + 2];
        float mean = w0 * mx + w1 * my + w2 * mz + bw[k];
        float var = w0 * w0 * Cxx + w1 * w1 * Cyy + w2 * w2 * Czz
                  + 2.f * (w0 * w1 * Cxy + w0 * w2 * Cxz + w1 * w2 * Cyz);
        float sc = gw[k] * rsqrtf(var + EPSV);
        par[128 + k] = sc;
        par[144 + k] = bew[k] - mean * sc;
    }
}

// Fused MFMA GEMM v4: VGPR-budgeted (no spills). Stream per-nt: gather ->
// MFMA -> bias/stats -> pack -> direct store, 1-deep software pipeline.
// __launch_bounds__(256,3) caps regalloc at ~170 VGPR (3 waves/SIMD).
__global__ __launch_bounds__(256, 3) void k_main(const ushort* __restrict__ ftb, const int* __restrict__ idxb,
                                                 const float4* __restrict__ qp, const float* __restrict__ W1,
                                                 const float* __restrict__ b1, const ushort* __restrict__ W2b,
                                                 const float* __restrict__ b2, const float* __restrict__ par,
                                                 float* __restrict__ bn2slots, __hip_bfloat16* __restrict__ z2) {
    __shared__ ushort enc_lds[64][72];   // 144B row stride (2-way bank, free)
    __shared__ float subs[64][3];
    __shared__ int nbr[64];
    const int tid = threadIdx.x;
    // bijective XCD swizzle: 4096 tiles, 8 XCDs, 512 contiguous tiles each
    const int tile = ((blockIdx.x & 7) << 9) | (blockIdx.x >> 3);
    const int pair0 = tile * 4;
    const int b = pair0 >> 12;
    const int lane = tid & 63, w = tid >> 6;
    const int lr = lane & 15, lg = lane >> 4;

    // prologue spread across all 4 waves
    if (lane < 16) {
        int pair = pair0 + w;
        int n = idxb[pair * 16 + lane];
        int r = w * 16 + lane;
        nbr[r] = n;
        float4 pn = qp[b * RN + n];
        float4 ps = qp[pair];
        subs[r][0] = pn.x - ps.x;
        subs[r][1] = pn.y - ps.y;
        subs[r][2] = pn.z - ps.z;
    }
    __syncthreads();

    const int cbase = w * 32;
    short8 af[12];
    #pragma unroll
    for (int ct = 0; ct < 2; ++ct)
        #pragma unroll
        for (int kt = 0; kt < 6; ++kt)
            af[ct * 6 + kt] = *(const short8*)(W2b + (size_t)(cbase + ct * 16 + lr) * 192 + kt * 32 + lg * 8);

    // enc_sub -> enc_lds (VALU overlaps af loads)
    for (int o = tid; o < 2048; o += 256) {
        int r = o >> 5, c2 = (o & 31) * 2;
        float z0 = fmaf(W1[c2 * 3],     subs[r][0], fmaf(W1[c2 * 3 + 1], subs[r][1], fmaf(W1[c2 * 3 + 2], subs[r][2], b1[c2])));
        float z1 = fmaf(W1[c2 * 3 + 3], subs[r][0], fmaf(W1[c2 * 3 + 4], subs[r][1], fmaf(W1[c2 * 3 + 5], subs[r][2], b1[c2 + 1])));
        float e0 = fmaxf(fmaf(z0, par[c2],     par[64 + c2]),     0.f);
        float e1 = fmaxf(fmaf(z1, par[c2 + 1], par[64 + c2 + 1]), 0.f);
        *(uint*)&enc_lds[r][c2] = (uint)f2bf(e0) | ((uint)f2bf(e1) << 16);
    }
    __syncthreads();

    float4 b2v[2];
    b2v[0] = *(const float4*)&b2[cbase + lg * 4];
    b2v[1] = *(const float4*)&b2[cbase + 16 + lg * 4];

    float st_s[8], st_q[8];
    #pragma unroll
    for (int i = 0; i < 8; ++i) { st_s[i] = 0.f; st_q[i] = 0.f; }

    // prefetch nt=0 gather fragments
    const ushort* fr0 = ftb + ((size_t)(b * RN + nbr[lr]) * 128) + lg * 8;
    short8 c0_ = *(const short8*)(fr0);
    short8 c1_ = *(const short8*)(fr0 + 32);
    short8 c2_ = *(const short8*)(fr0 + 64);
    short8 c3_ = *(const short8*)(fr0 + 96);

    #pragma unroll 1
    for (int nt = 0; nt < 4; ++nt) {
        short8 n0_ = c0_, n1_ = c1_, n2_ = c2_, n3_ = c3_;
        if (nt < 3) {   // 1-deep pipeline: issue next-nt gathers now
            const ushort* fr = ftb + ((size_t)(b * RN + nbr[(nt + 1) * 16 + lr]) * 128) + lg * 8;
            n0_ = *(const short8*)(fr);
            n1_ = *(const short8*)(fr + 32);
            n2_ = *(const short8*)(fr + 64);
            n3_ = *(const short8*)(fr + 96);
        }
        const int r = nt * 16 + lr;
        short8 be0 = *(const short8*)&enc_lds[r][lg * 8];
        short8 be1 = *(const short8*)&enc_lds[r][32 + lg * 8];
        const size_t row = (size_t)pair0 * 16 + r;
        #pragma unroll
        for (int ct = 0; ct < 2; ++ct) {
            f32x4 acc = {0.f, 0.f, 0.f, 0.f};
            acc = __builtin_amdgcn_mfma_f32_16x16x32_bf16(af[ct * 6 + 0], c0_, acc, 0, 0, 0);
            acc = __builtin_amdgcn_mfma_f32_16x16x32_bf16(af[ct * 6 + 1], c1_, acc, 0, 0, 0);
            acc = __builtin_amdgcn_mfma_f32_16x16x32_bf16(af[ct * 6 + 2], c2_, acc, 0, 0, 0);
            acc = __builtin_amdgcn_mfma_f32_16x16x32_bf16(af[ct * 6 + 3], c3_, acc, 0, 0, 0);
            acc = __builtin_amdgcn_mfma_f32_16x16x32_bf16(af[ct * 6 + 4], be0, acc, 0, 0, 0);
            acc = __builtin_amdgcn_mfma_f32_16x16x32_bf16(af[ct * 6 + 5], be1, acc, 0, 0, 0);
            const int c0ch = cbase + ct * 16 + lg * 4;
            union { __hip_bfloat16 h[4]; uint2 u2; } pk;
            const float4 bb = b2v[ct];
            float vb[4] = {bb.x, bb.y, bb.z, bb.w};
            #pragma unroll
            for (int cc = 0; cc < 4; ++cc) {
                float v = acc[cc] + vb[cc];
                st_s[ct * 4 + cc] += v;
                st_q[ct * 4 + cc] = fmaf(v, v, st_q[ct * 4 + cc]);
                pk.h[cc] = __float2bfloat16(v);
            }
            *(uint2*)(z2 + row * CC + c0ch) = pk.u2;
        }
        c0_ = n0_; c1_ = n1_; c2_ = n2_; c3_ = n3_;
    }
    // BN2 partial stats: reduce over the 16 rows, one atomic per channel
    #pragma unroll
    for (int i = 0; i < 8; ++i) {
        float s = st_s[i], q = st_q[i];
        #pragma unroll
        for (int m = 1; m < 16; m <<= 1) { s += __shfl_xor(s, m); q += __shfl_xor(q, m); }
        if (lr == 0) {
            int ct = i >> 2, cc = i & 3;
            int c = cbase + ct * 16 + lg * 4 + cc;
            atomicAdd(&bn2slots[(tile & 63) * 256 + c * 2], s);
            atomicAdd(&bn2slots[(tile & 63) * 256 + c * 2 + 1], q);
        }
    }
}

__global__ void k_bn2(const float* __restrict__ slots, const float* __restrict__ g2,
                      const float* __restrict__ be2, float* __restrict__ par) {
    __shared__ float red[256];
    int tid = threadIdx.x;
    float v = 0.f;
    for (int s = 0; s < 64; ++s) v += slots[s * 256 + tid];
    red[tid] = v;
    __syncthreads();
    if (tid < 128) {
        const float invN = 1.0f / (float)NROWS;
        float mean = red[2 * tid] * invN;
        float var = red[2 * tid + 1] * invN - mean * mean;
        float sc = g2[tid] * rsqrtf(var + EPSV);
        par[160 + tid] = sc;
        par[288 + tid] = be2[tid] - mean * sc;
    }
}

// Epilogue: BN2+ReLU, weight by w_diag, sum over K, residual, transpose to (B,C,N).
__global__ __launch_bounds__(256) void k_out(const __hip_bfloat16* __restrict__ z2, const float* __restrict__ zw_raw,
                                             const float* __restrict__ par, const float* __restrict__ F_E,
                                             float* __restrict__ out) {
    __shared__ float wd[32][16];
    __shared__ float outs[32][129];
    const int tid = threadIdx.x;
    const int b = blockIdx.x >> 7;
    const int r0 = (blockIdx.x & 127) * 32;
    const int rowbase = (b * RN + r0) * 16;
    for (int o = tid; o < 512; o += 256) {
        int rr = o >> 4, k = o & 15;
        wd[rr][k] = fmaxf(fmaf(zw_raw[rowbase + o], par[128 + k], par[144 + k]), 0.f);
    }
    __syncthreads();
    const int c0 = (tid & 63) * 2;
    const int rh = tid >> 6;
    const float sc0 = par[160 + c0], sh0 = par[288 + c0];
    const float sc1 = par[160 + c0 + 1], sh1 = par[288 + c0 + 1];
    for (int rr = rh; rr < 32; rr += 4) {
        float a0 = 0.f, a1 = 0.f;
        const __hip_bfloat16* zp = z2 + ((size_t)rowbase + rr * 16) * CC + c0;
        #pragma unroll
        for (int k = 0; k < 16; ++k) {
            unsigned int uu = *(const unsigned int*)(zp + k * CC);
            float z0 = __uint_as_float(uu << 16);
            float z1 = __uint_as_float(uu & 0xFFFF0000u);
            float w = wd[rr][k];
            a0 += fmaxf(fmaf(z0, sc0, sh0), 0.f) * w;
            a1 += fmaxf(fmaf(z1, sc1, sh1), 0.f) * w;
        }
        outs[rr][c0] = a0; outs[rr][c0 + 1] = a1;
    }
    __syncthreads();
    for (int o = tid; o < 4096; o += 256) {
        int c = o >> 5, rr = o & 31;
        size_t oi = ((size_t)b * CC + c) * RN + r0 + rr;
        out[oi] = outs[rr][c] + F_E[oi];
    }
}

extern "C" void kernel_launch(void* const* d_in, const int* in_sizes, int n_in,
                              void* d_out, int out_size, void* d_ws, size_t ws_size,
                              hipStream_t stream) {
    const float* F_E = (const float*)d_in[0];
    const float* Qp  = (const float*)d_in[1];
    const float* W1  = (const float*)d_in[2];
    const float* b1  = (const float*)d_in[3];
    const float* g1  = (const float*)d_in[4];
    const float* be1 = (const float*)d_in[5];
    const float* W2  = (const float*)d_in[6];
    const float* b2  = (const float*)d_in[7];
    const float* g2  = (const float*)d_in[8];
    const float* be2 = (const float*)d_in[9];
    const float* Ww  = (const float*)d_in[10];
    const float* bw  = (const float*)d_in[11];
    const float* gw  = (const float*)d_in[12];
    const float* bew = (const float*)d_in[13];
    float* out = (float*)d_out;
    float* wsf = (float*)d_ws;

    float* bn2slots   = wsf;
    float* statslots  = wsf + 16384;
    float* par        = wsf + 17152;
    ushort* W2b       = (ushort*)(wsf + 17664);
    float4* qpack     = (float4*)(wsf + 32768);
    int* idxb         = (int*)(wsf + 98304);
    float* zw_raw     = wsf + 360448;
    ushort* ftb       = (ushort*)(wsf + 622592);
    __hip_bfloat16* z2 = (__hip_bfloat16*)(wsf + 1671168);

    hipMemsetAsync(d_ws, 0, 17152 * sizeof(float), stream);
    k_prep<<<160, 256, 0, stream>>>(Qp, qpack, W2, W2b);
    k_transpose<<<2048, 256, 0, stream>>>(F_E, ftb);
    k_knn<<<4096, 256, 0, stream>>>(qpack, idxb, zw_raw, statslots, Ww, bw);
    k_bn1<<<1, 128, 0, stream>>>(statslots, W1, b1, g1, be1, Ww, bw, gw, bew, par);
    k_main<<<4096, 256, 0, stream>>>(ftb, idxb, qpack, W1, b1, W2b, b2, par, bn2slots, z2);
    k_bn2<<<1, 256, 0, stream>>>(bn2slots, g2, be2, par);
    k_out<<<512, 256, 0, stream>>>(z2, zw_raw, par, F_E, out);
}